// Round 12
// baseline (354.078 us; speedup 1.0000x reference)
//
#include <hip/hip_runtime.h>
#include <hip/hip_fp16.h>
#include <cstddef>

// ---------------------------------------------------------------------------
// GCN: out = relu(Â relu(Â relu(Â (x W0)) W1) W2),  Â = D^-1/2 (A+I) D^-1/2
// R12: agg octet scheme — lane = 8 fp16 features (16B), 8-lane octet per
// edge row, ONE load instr = 8 rows (1KB), one shfl per 8 edges, 4-group
// batching (4KB in flight/wave). fp16 t' (R11), norm factored (R8), CSR via
// atomic-free counting sort (R7).
// ---------------------------------------------------------------------------

constexpr int NBLK  = 512;   // blocks for pass A / pass B (mapping must match)
constexpr int NPMAX = 512;   // max partitions (256 nodes each)

// Pass A: per-block partition histogram (LDS only).
__global__ __launch_bounds__(256) void passA_kernel(const int* __restrict__ dst, int E,
                                                    int* __restrict__ histG, int NP) {
    __shared__ int hist[NPMAX];
    for (int i = threadIdx.x; i < NP; i += 256) hist[i] = 0;
    __syncthreads();
    for (int e = blockIdx.x * 256 + threadIdx.x; e < E; e += NBLK * 256)
        atomicAdd(&hist[dst[e] >> 8], 1);
    __syncthreads();
    for (int p = threadIdx.x; p < NP; p += 256)
        histG[p * NBLK + blockIdx.x] = hist[p];   // p-major, block-minor
}

// ---- exclusive scan (3-kernel, 4096 items/block) ----
constexpr int SCAN_ITEMS = 16;
constexpr int SCAN_CHUNK = 256 * SCAN_ITEMS;  // 4096

__global__ __launch_bounds__(256) void scan1_kernel(const int* __restrict__ in,
                                                    int* __restrict__ outp,
                                                    int* __restrict__ blockSums, int n) {
    __shared__ int sh[256];
    int tbase = blockIdx.x * SCAN_CHUNK + threadIdx.x * SCAN_ITEMS;
    int vals[SCAN_ITEMS];
    int tsum = 0;
#pragma unroll
    for (int j = 0; j < SCAN_ITEMS; ++j) {
        int idx = tbase + j;
        int v = (idx < n) ? in[idx] : 0;
        vals[j] = tsum;
        tsum += v;
    }
    sh[threadIdx.x] = tsum;
    __syncthreads();
    for (int off = 1; off < 256; off <<= 1) {
        int v = (threadIdx.x >= off) ? sh[threadIdx.x - off] : 0;
        __syncthreads();
        sh[threadIdx.x] += v;
        __syncthreads();
    }
    int texcl = sh[threadIdx.x] - tsum;
    if (threadIdx.x == 255) blockSums[blockIdx.x] = sh[255];
#pragma unroll
    for (int j = 0; j < SCAN_ITEMS; ++j) {
        int idx = tbase + j;
        if (idx < n) outp[idx] = texcl + vals[j];
    }
}

__global__ void scan2_kernel(int* __restrict__ blockSums, int nb) {
    if (threadIdx.x == 0 && blockIdx.x == 0) {
        int run = 0;
        for (int i = 0; i < nb; ++i) { int v = blockSums[i]; blockSums[i] = run; run += v; }
    }
}

__global__ __launch_bounds__(256) void scan3_kernel(int* __restrict__ ptr,
                                                    const int* __restrict__ blockSums,
                                                    int n, int E) {
    int idx = blockIdx.x * blockDim.x + threadIdx.x;
    if (idx < n) ptr[idx] += blockSums[idx / SCAN_CHUNK];
    if (idx == 0) ptr[n] = E;   // sentinel
}

// Pass B: deterministic scatter to partition-sorted order. LDS cursors only.
// Record = (dstLocal<<17) | src  (src < 2^17, dstLocal < 256) -> 4 bytes.
__global__ __launch_bounds__(256) void passB_kernel(const int* __restrict__ src,
                                                    const int* __restrict__ dst,
                                                    const int* __restrict__ histS,
                                                    unsigned* __restrict__ recP,
                                                    int E, int NP) {
    __shared__ int cur[NPMAX];
    for (int i = threadIdx.x; i < NP; i += 256) cur[i] = histS[i * NBLK + blockIdx.x];
    __syncthreads();
    for (int e = blockIdx.x * 256 + threadIdx.x; e < E; e += NBLK * 256) {
        int s = src[e], d = dst[e];
        int slot = atomicAdd(&cur[d >> 8], 1);   // LDS atomic, block-private run
        recP[slot] = ((unsigned)(d & 255) << 17) | (unsigned)s;
    }
}

// Pass C: one block per partition. Per-node degree count (LDS) -> dinv ->
// LDS scan -> rowptr slice -> scatter src into per-node CSR order.
__global__ __launch_bounds__(256) void passC_kernel(const unsigned* __restrict__ recP,
                                                    const int* __restrict__ histS,
                                                    int* __restrict__ rec,
                                                    int* __restrict__ rowptr,
                                                    float* __restrict__ dinv,
                                                    int N, int E) {
    __shared__ int cntL[256];
    __shared__ int sh[256];
    const int p = blockIdx.x;
    const int S    = histS[p * NBLK];
    const int Eend = histS[(p + 1) * NBLK];   // sentinel covers last partition
    cntL[threadIdx.x] = 0;
    __syncthreads();
    for (int i = S + threadIdx.x; i < Eend; i += 256)
        atomicAdd(&cntL[recP[i] >> 17], 1);
    __syncthreads();
    int v = cntL[threadIdx.x];                // this node's degree
    int node = p * 256 + threadIdx.x;
    if (node < N) dinv[node] = rsqrtf((float)v + 1.0f);  // +1 self-loop
    sh[threadIdx.x] = v;
    __syncthreads();
    for (int off = 1; off < 256; off <<= 1) {
        int u = (threadIdx.x >= off) ? sh[threadIdx.x - off] : 0;
        __syncthreads();
        sh[threadIdx.x] += u;
        __syncthreads();
    }
    int excl = sh[threadIdx.x] - v;           // exclusive within partition
    if (node < N) rowptr[node] = S + excl;
    if (p == 0 && threadIdx.x == 0) rowptr[N] = E;
    __syncthreads();
    cntL[threadIdx.x] = S + excl;             // reuse as cursor
    __syncthreads();
    for (int i = S + threadIdx.x; i < Eend; i += 256) {
        unsigned r = recP[i];
        int slot = atomicAdd(&cntL[r >> 17], 1);
        rec[slot] = (int)(r & 0x1FFFFu);
    }
}

// ---------------------------------------------------------------------------
// Register-tiled GEMM, fused row scale + FP16 convert:
// outH[row] = (__half)( (A[row] @ W) * dinv[row] ).
// Block = 256 thr = 16x16 grid, 4x4 outputs/thread => 64 rows x 64 cols.
// ---------------------------------------------------------------------------
template <int K, int M>
__global__ __launch_bounds__(256) void gemm_kernel(const float* __restrict__ A,
                                                   const float* __restrict__ W,
                                                   const float* __restrict__ dinv,
                                                   __half* __restrict__ outH, int N) {
    constexpr int KC = 64;
    constexpr int SA = 68;
    __shared__ float Ws[K * M];
    __shared__ float As[KC * SA];   // As[k][row]
    for (int i = threadIdx.x; i < K * M; i += 256) Ws[i] = W[i];

    const int tr = threadIdx.x & 15;
    const int tc = threadIdx.x >> 4;
    const int r0 = tr * 4, c0 = tc * 4;
    const int row0 = blockIdx.x * 64;
    const bool colAct = (c0 < M);

    float acc[4][4] = {};

    for (int k0 = 0; k0 < K; k0 += KC) {
        __syncthreads();
        {
            const int kq = threadIdx.x & 15;
            const int rr = threadIdx.x >> 4;
#pragma unroll
            for (int p = 0; p < 4; ++p) {
                int row = rr + p * 16;
                int grow = row0 + row;
                float4 v = make_float4(0.f, 0.f, 0.f, 0.f);
                if (grow < N)
                    v = *reinterpret_cast<const float4*>(&A[(size_t)grow * K + k0 + kq * 4]);
                As[(kq * 4 + 0) * SA + row] = v.x;
                As[(kq * 4 + 1) * SA + row] = v.y;
                As[(kq * 4 + 2) * SA + row] = v.z;
                As[(kq * 4 + 3) * SA + row] = v.w;
            }
        }
        __syncthreads();
        if (colAct) {
#pragma unroll 8
            for (int kk = 0; kk < KC; ++kk) {
                float4 a = *reinterpret_cast<const float4*>(&As[kk * SA + r0]);
                float4 b = *reinterpret_cast<const float4*>(&Ws[(k0 + kk) * M + c0]);
                acc[0][0] = fmaf(a.x, b.x, acc[0][0]); acc[0][1] = fmaf(a.x, b.y, acc[0][1]);
                acc[0][2] = fmaf(a.x, b.z, acc[0][2]); acc[0][3] = fmaf(a.x, b.w, acc[0][3]);
                acc[1][0] = fmaf(a.y, b.x, acc[1][0]); acc[1][1] = fmaf(a.y, b.y, acc[1][1]);
                acc[1][2] = fmaf(a.y, b.z, acc[1][2]); acc[1][3] = fmaf(a.y, b.w, acc[1][3]);
                acc[2][0] = fmaf(a.z, b.x, acc[2][0]); acc[2][1] = fmaf(a.z, b.y, acc[2][1]);
                acc[2][2] = fmaf(a.z, b.z, acc[2][2]); acc[2][3] = fmaf(a.z, b.w, acc[2][3]);
                acc[3][0] = fmaf(a.w, b.x, acc[3][0]); acc[3][1] = fmaf(a.w, b.y, acc[3][1]);
                acc[3][2] = fmaf(a.w, b.z, acc[3][2]); acc[3][3] = fmaf(a.w, b.w, acc[3][3]);
            }
        }
    }

    if (colAct) {
#pragma unroll
        for (int i = 0; i < 4; ++i) {
            int grow = row0 + r0 + i;
            if (grow < N) {
                float s = dinv[grow];
                __half2 p0 = __floats2half2_rn(acc[i][0] * s, acc[i][1] * s);
                __half2 p1 = __floats2half2_rn(acc[i][2] * s, acc[i][3] * s);
                uint2 o;
                o.x = *reinterpret_cast<unsigned*>(&p0);
                o.y = *reinterpret_cast<unsigned*>(&p1);
                *reinterpret_cast<uint2*>(&outH[(size_t)grow * M + c0]) = o;
            }
        }
    }
}

// ---------------------------------------------------------------------------
// Octet gather aggregation from FP16 t', wave-convergent.
// One wave per node. Lane = 8 fp16 features (16B uint4); 8-lane octet covers
// one 128B row; one load instruction gathers 8 different rows (1KB). One
// shfl per 8 edges (per-lane index). 4-group batching -> 4KB in flight/wave.
// out[n] = relu( dinv[n] * ( sum_e t'[src_e] + t'[n] ) )   (fp32 out)
// ---------------------------------------------------------------------------
template <int D>
__global__ __launch_bounds__(256) void agg_kernel(const __half* __restrict__ t,
                                                  const int* __restrict__ rowptr,
                                                  const int* __restrict__ rec,
                                                  const float* __restrict__ dinv,
                                                  float* __restrict__ out, int N) {
    int n = blockIdx.x * 4 + (threadIdx.x >> 6);
    if (n >= N) return;
    const int lane = threadIdx.x & 63;
    const int o  = lane >> 3;          // octet 0..7
    const int fl = (lane & 7) * 8;     // feature base (8 fp16 = 16B)
    const bool act = (fl < D);
    const int beg = rowptr[n], end = rowptr[n + 1];
    const int deg = end - beg;

    float a0 = 0.f, a1 = 0.f, a2 = 0.f, a3 = 0.f;
    float a4 = 0.f, a5 = 0.f, a6 = 0.f, a7 = 0.f;

#define ACC_U4(R)                                                              \
    {                                                                          \
        float2 f0 = __half22float2(*reinterpret_cast<const __half2*>(&R.x));   \
        float2 f1 = __half22float2(*reinterpret_cast<const __half2*>(&R.y));   \
        float2 f2 = __half22float2(*reinterpret_cast<const __half2*>(&R.z));   \
        float2 f3 = __half22float2(*reinterpret_cast<const __half2*>(&R.w));   \
        a0 += f0.x; a1 += f0.y; a2 += f1.x; a3 += f1.y;                        \
        a4 += f2.x; a5 += f2.y; a6 += f3.x; a7 += f3.y;                        \
    }

    if (o == 0 && act) {   // self-loop: t'[n]
        uint4 r = *reinterpret_cast<const uint4*>(&t[(size_t)n * D + fl]);
        ACC_U4(r);
    }

    for (int base = 0; base < deg; base += 64) {
        int idx = base + lane;
        int rc = (idx < deg) ? rec[beg + idx] : 0;   // coalesced, 64 edges/load
        const int lim = min(deg - base, 64);         // wave-uniform
        const int G = lim >> 3;                      // full groups of 8 (uniform)
        int g = 0;
        for (; g + 4 <= G; g += 4) {                 // 4-group batch: 4KB in flight
            int e0 = __shfl(rc, (g + 0) * 8 + o);
            int e1 = __shfl(rc, (g + 1) * 8 + o);
            int e2 = __shfl(rc, (g + 2) * 8 + o);
            int e3 = __shfl(rc, (g + 3) * 8 + o);
            if (act) {
                uint4 r0 = *reinterpret_cast<const uint4*>(&t[(size_t)e0 * D + fl]);
                uint4 r1 = *reinterpret_cast<const uint4*>(&t[(size_t)e1 * D + fl]);
                uint4 r2 = *reinterpret_cast<const uint4*>(&t[(size_t)e2 * D + fl]);
                uint4 r3 = *reinterpret_cast<const uint4*>(&t[(size_t)e3 * D + fl]);
                ACC_U4(r0); ACC_U4(r1); ACC_U4(r2); ACC_U4(r3);
            }
        }
        for (; g < G; ++g) {
            int e = __shfl(rc, g * 8 + o);
            if (act) {
                uint4 r = *reinterpret_cast<const uint4*>(&t[(size_t)e * D + fl]);
                ACC_U4(r);
            }
        }
        // tail: r in [0,8); one uniform step, clamped shfl + predicated acc
        if (lim & 7) {
            int jj = G * 8 + o;
            int jc = (jj < lim) ? jj : 0;
            int e = __shfl(rc, jc);
            if (act && jj < lim) {
                uint4 r = *reinterpret_cast<const uint4*>(&t[(size_t)e * D + fl]);
                ACC_U4(r);
            }
        }
    }
#undef ACC_U4

#define RED(A) A += __shfl_xor(A, 8); A += __shfl_xor(A, 16); A += __shfl_xor(A, 32);
    RED(a0) RED(a1) RED(a2) RED(a3) RED(a4) RED(a5) RED(a6) RED(a7)
#undef RED

    if (o == 0 && act) {
        float di = dinv[n];
        float4 o0 = make_float4(fmaxf(di * a0, 0.f), fmaxf(di * a1, 0.f),
                                fmaxf(di * a2, 0.f), fmaxf(di * a3, 0.f));
        float4 o1 = make_float4(fmaxf(di * a4, 0.f), fmaxf(di * a5, 0.f),
                                fmaxf(di * a6, 0.f), fmaxf(di * a7, 0.f));
        *reinterpret_cast<float4*>(&out[(size_t)n * D + fl]) = o0;
        *reinterpret_cast<float4*>(&out[(size_t)n * D + fl + 4]) = o1;
    }
}

extern "C" void kernel_launch(void* const* d_in, const int* in_sizes, int n_in,
                              void* d_out, int out_size, void* d_ws, size_t ws_size,
                              hipStream_t stream) {
    const float* x  = (const float*)d_in[0];
    const int*   ei = (const int*)d_in[1];   // [2, E] row-major, int32
    const float* W0 = (const float*)d_in[2]; // [128,64]
    const float* W1 = (const float*)d_in[3]; // [64,64]
    const float* W2 = (const float*)d_in[4]; // [64,40]
    float* out = (float*)d_out;

    const int N = in_sizes[0] / 128;
    const int E = in_sizes[1] / 2;
    const int* src = ei;
    const int* dst = ei + E;
    const int NP = (N + 255) / 256;          // 391 partitions of 256 nodes
    const int histItems = NP * NBLK;         // 200192

    char* w = (char*)d_ws;
    size_t off = 0;
    auto alloc = [&](size_t bytes) {
        void* p = w + off;
        off += bytes;
        off = (off + 255) & ~(size_t)255;
        return p;
    };
    float*    dinv   = (float*)alloc((size_t)N * 4);
    int*      histG  = (int*)alloc((size_t)histItems * 4);
    int*      histS  = (int*)alloc((size_t)(histItems + 1) * 4);
    int*      rowptr = (int*)alloc((size_t)(N + 1) * 4);
    int*      bsums  = (int*)alloc(4096);
    int*      rec    = (int*)alloc((size_t)E * 4);     // per-node CSR (persists)
    float*    B2     = (float*)alloc((size_t)N * 64 * 4);   // fp32 agg-out / gemm-in
    __half*   tP     = (__half*)alloc((size_t)N * 64 * 2);  // fp16 t' (gathered)
    unsigned* recP   = (unsigned*)tP;   // partition-sorted recs, dead before gemm0

    // --- CSR build (counting sort, zero global atomics; reused by 3 layers) ---
    passA_kernel<<<NBLK, 256, 0, stream>>>(dst, E, histG, NP);
    const int nCh = (histItems + SCAN_CHUNK - 1) / SCAN_CHUNK;
    scan1_kernel<<<nCh, 256, 0, stream>>>(histG, histS, bsums, histItems);
    scan2_kernel<<<1, 64, 0, stream>>>(bsums, nCh);
    scan3_kernel<<<(histItems + 255) / 256, 256, 0, stream>>>(histS, bsums, histItems, E);
    passB_kernel<<<NBLK, 256, 0, stream>>>(src, dst, histS, recP, E, NP);
    passC_kernel<<<NP, 256, 0, stream>>>(recP, histS, rec, rowptr, dinv, N, E);

    const int gemmGrid = (N + 63) / 64;

    // --- layer 0 ---
    gemm_kernel<128, 64><<<gemmGrid, 256, 0, stream>>>(x, W0, dinv, tP, N);
    agg_kernel<64><<<(N + 3) / 4, 256, 0, stream>>>(tP, rowptr, rec, dinv, B2, N);

    // --- layer 1 ---
    gemm_kernel<64, 64><<<gemmGrid, 256, 0, stream>>>(B2, W1, dinv, tP, N);
    agg_kernel<64><<<(N + 3) / 4, 256, 0, stream>>>(tP, rowptr, rec, dinv, B2, N);

    // --- layer 2 ---
    gemm_kernel<64, 40><<<gemmGrid, 256, 0, stream>>>(B2, W2, dinv, tP, N);
    agg_kernel<40><<<(N + 3) / 4, 256, 0, stream>>>(tP, rowptr, rec, dinv, out, N);
}

// Round 13
// 336.664 us; speedup vs baseline: 1.0517x; 1.0517x over previous
//
#include <hip/hip_runtime.h>
#include <hip/hip_fp16.h>
#include <cstddef>

// ---------------------------------------------------------------------------
// GCN: out = relu(Â relu(Â relu(Â (x W0)) W1) W2),  Â = D^-1/2 (A+I) D^-1/2
// R13: agg reverted to R11 quarter-wave form (proven best). CSR-build lean:
// scan2 is a single-wave shfl scan (was 1-thread serial, ~12us), scan3
// deleted (block-sum correction folded into passB/passC). fp16 t' (R11),
// norm factored (R8), counting-sort CSR with zero global atomics (R7).
// ---------------------------------------------------------------------------

constexpr int NBLK  = 512;   // blocks for pass A / pass B (mapping must match)
constexpr int NPMAX = 512;   // max partitions (256 nodes each)

// Pass A: per-block partition histogram (LDS only).
__global__ __launch_bounds__(256) void passA_kernel(const int* __restrict__ dst, int E,
                                                    int* __restrict__ histG, int NP) {
    __shared__ int hist[NPMAX];
    for (int i = threadIdx.x; i < NP; i += 256) hist[i] = 0;
    __syncthreads();
    for (int e = blockIdx.x * 256 + threadIdx.x; e < E; e += NBLK * 256)
        atomicAdd(&hist[dst[e] >> 8], 1);
    __syncthreads();
    for (int p = threadIdx.x; p < NP; p += 256)
        histG[p * NBLK + blockIdx.x] = hist[p];   // p-major, block-minor
}

// ---- scan: per-chunk exclusive (scan1) + wave scan of chunk sums (scan2) ----
constexpr int SCAN_ITEMS = 16;
constexpr int SCAN_CHUNK = 256 * SCAN_ITEMS;  // 4096 (= 1<<12)

__global__ __launch_bounds__(256) void scan1_kernel(const int* __restrict__ in,
                                                    int* __restrict__ outp,
                                                    int* __restrict__ blockSums, int n) {
    __shared__ int sh[256];
    int tbase = blockIdx.x * SCAN_CHUNK + threadIdx.x * SCAN_ITEMS;
    int vals[SCAN_ITEMS];
    int tsum = 0;
#pragma unroll
    for (int j = 0; j < SCAN_ITEMS; ++j) {
        int idx = tbase + j;
        int v = (idx < n) ? in[idx] : 0;
        vals[j] = tsum;
        tsum += v;
    }
    sh[threadIdx.x] = tsum;
    __syncthreads();
    for (int off = 1; off < 256; off <<= 1) {
        int v = (threadIdx.x >= off) ? sh[threadIdx.x - off] : 0;
        __syncthreads();
        sh[threadIdx.x] += v;
        __syncthreads();
    }
    int texcl = sh[threadIdx.x] - tsum;
    if (threadIdx.x == 255) blockSums[blockIdx.x] = sh[255];
#pragma unroll
    for (int j = 0; j < SCAN_ITEMS; ++j) {
        int idx = tbase + j;
        if (idx < n) outp[idx] = texcl + vals[j];
    }
}

// single-wave exclusive scan of the (<=64) chunk sums; serial fallback else
__global__ void scan2_kernel(int* __restrict__ blockSums, int nb) {
    int lane = threadIdx.x & 63;
    if (nb <= 64) {
        int orig = (lane < nb) ? blockSums[lane] : 0;
        int v = orig;
#pragma unroll
        for (int off = 1; off < 64; off <<= 1) {
            int u = __shfl_up(v, off);
            if (lane >= off) v += u;
        }
        if (lane < nb) blockSums[lane] = v - orig;   // exclusive
    } else if (lane == 0) {
        int run = 0;
        for (int i = 0; i < nb; ++i) { int v = blockSums[i]; blockSums[i] = run; run += v; }
    }
}

// Pass B: deterministic scatter to partition-sorted order. LDS cursors only.
// histS is the RAW per-chunk scan; correction = + bsums[k >> 12].
// Record = (dstLocal<<17) | src  (src < 2^17, dstLocal < 256) -> 4 bytes.
__global__ __launch_bounds__(256) void passB_kernel(const int* __restrict__ src,
                                                    const int* __restrict__ dst,
                                                    const int* __restrict__ histS,
                                                    const int* __restrict__ bsums,
                                                    unsigned* __restrict__ recP,
                                                    int E, int NP) {
    __shared__ int cur[NPMAX];
    for (int i = threadIdx.x; i < NP; i += 256) {
        int k = i * NBLK + blockIdx.x;
        cur[i] = histS[k] + bsums[k >> 12];
    }
    __syncthreads();
    for (int e = blockIdx.x * 256 + threadIdx.x; e < E; e += NBLK * 256) {
        int s = src[e], d = dst[e];
        int slot = atomicAdd(&cur[d >> 8], 1);   // LDS atomic, block-private run
        recP[slot] = ((unsigned)(d & 255) << 17) | (unsigned)s;
    }
}

// Pass C: one block per partition. Per-node degree count (LDS) -> dinv ->
// LDS scan -> rowptr slice -> scatter src into per-node CSR order.
__global__ __launch_bounds__(256) void passC_kernel(const unsigned* __restrict__ recP,
                                                    const int* __restrict__ histS,
                                                    const int* __restrict__ bsums,
                                                    int* __restrict__ rec,
                                                    int* __restrict__ rowptr,
                                                    float* __restrict__ dinv,
                                                    int N, int E, int NP) {
    __shared__ int cntL[256];
    __shared__ int sh[256];
    const int p = blockIdx.x;
    int kS = p * NBLK;
    const int S = histS[kS] + bsums[kS >> 12];
    int Eend;
    if (p == NP - 1) Eend = E;
    else { int kE = (p + 1) * NBLK; Eend = histS[kE] + bsums[kE >> 12]; }
    cntL[threadIdx.x] = 0;
    __syncthreads();
    for (int i = S + threadIdx.x; i < Eend; i += 256)
        atomicAdd(&cntL[recP[i] >> 17], 1);
    __syncthreads();
    int v = cntL[threadIdx.x];                // this node's degree
    int node = p * 256 + threadIdx.x;
    if (node < N) dinv[node] = rsqrtf((float)v + 1.0f);  // +1 self-loop
    sh[threadIdx.x] = v;
    __syncthreads();
    for (int off = 1; off < 256; off <<= 1) {
        int u = (threadIdx.x >= off) ? sh[threadIdx.x - off] : 0;
        __syncthreads();
        sh[threadIdx.x] += u;
        __syncthreads();
    }
    int excl = sh[threadIdx.x] - v;           // exclusive within partition
    if (node < N) rowptr[node] = S + excl;
    if (p == 0 && threadIdx.x == 0) rowptr[N] = E;
    __syncthreads();
    cntL[threadIdx.x] = S + excl;             // reuse as cursor
    __syncthreads();
    for (int i = S + threadIdx.x; i < Eend; i += 256) {
        unsigned r = recP[i];
        int slot = atomicAdd(&cntL[r >> 17], 1);
        rec[slot] = (int)(r & 0x1FFFFu);
    }
}

// ---------------------------------------------------------------------------
// Register-tiled GEMM, fused row scale + FP16 convert:
// outH[row] = (__half)( (A[row] @ W) * dinv[row] ).
// Block = 256 thr = 16x16 grid, 4x4 outputs/thread => 64 rows x 64 cols.
// ---------------------------------------------------------------------------
template <int K, int M>
__global__ __launch_bounds__(256) void gemm_kernel(const float* __restrict__ A,
                                                   const float* __restrict__ W,
                                                   const float* __restrict__ dinv,
                                                   __half* __restrict__ outH, int N) {
    constexpr int KC = 64;
    constexpr int SA = 68;
    __shared__ float Ws[K * M];
    __shared__ float As[KC * SA];   // As[k][row]
    for (int i = threadIdx.x; i < K * M; i += 256) Ws[i] = W[i];

    const int tr = threadIdx.x & 15;
    const int tc = threadIdx.x >> 4;
    const int r0 = tr * 4, c0 = tc * 4;
    const int row0 = blockIdx.x * 64;
    const bool colAct = (c0 < M);

    float acc[4][4] = {};

    for (int k0 = 0; k0 < K; k0 += KC) {
        __syncthreads();
        {
            const int kq = threadIdx.x & 15;
            const int rr = threadIdx.x >> 4;
#pragma unroll
            for (int p = 0; p < 4; ++p) {
                int row = rr + p * 16;
                int grow = row0 + row;
                float4 v = make_float4(0.f, 0.f, 0.f, 0.f);
                if (grow < N)
                    v = *reinterpret_cast<const float4*>(&A[(size_t)grow * K + k0 + kq * 4]);
                As[(kq * 4 + 0) * SA + row] = v.x;
                As[(kq * 4 + 1) * SA + row] = v.y;
                As[(kq * 4 + 2) * SA + row] = v.z;
                As[(kq * 4 + 3) * SA + row] = v.w;
            }
        }
        __syncthreads();
        if (colAct) {
#pragma unroll 8
            for (int kk = 0; kk < KC; ++kk) {
                float4 a = *reinterpret_cast<const float4*>(&As[kk * SA + r0]);
                float4 b = *reinterpret_cast<const float4*>(&Ws[(k0 + kk) * M + c0]);
                acc[0][0] = fmaf(a.x, b.x, acc[0][0]); acc[0][1] = fmaf(a.x, b.y, acc[0][1]);
                acc[0][2] = fmaf(a.x, b.z, acc[0][2]); acc[0][3] = fmaf(a.x, b.w, acc[0][3]);
                acc[1][0] = fmaf(a.y, b.x, acc[1][0]); acc[1][1] = fmaf(a.y, b.y, acc[1][1]);
                acc[1][2] = fmaf(a.y, b.z, acc[1][2]); acc[1][3] = fmaf(a.y, b.w, acc[1][3]);
                acc[2][0] = fmaf(a.z, b.x, acc[2][0]); acc[2][1] = fmaf(a.z, b.y, acc[2][1]);
                acc[2][2] = fmaf(a.z, b.z, acc[2][2]); acc[2][3] = fmaf(a.z, b.w, acc[2][3]);
                acc[3][0] = fmaf(a.w, b.x, acc[3][0]); acc[3][1] = fmaf(a.w, b.y, acc[3][1]);
                acc[3][2] = fmaf(a.w, b.z, acc[3][2]); acc[3][3] = fmaf(a.w, b.w, acc[3][3]);
            }
        }
    }

    if (colAct) {
#pragma unroll
        for (int i = 0; i < 4; ++i) {
            int grow = row0 + r0 + i;
            if (grow < N) {
                float s = dinv[grow];
                __half2 p0 = __floats2half2_rn(acc[i][0] * s, acc[i][1] * s);
                __half2 p1 = __floats2half2_rn(acc[i][2] * s, acc[i][3] * s);
                uint2 o;
                o.x = *reinterpret_cast<unsigned*>(&p0);
                o.y = *reinterpret_cast<unsigned*>(&p1);
                *reinterpret_cast<uint2*>(&outH[(size_t)grow * M + c0]) = o;
            }
        }
    }
}

// ---------------------------------------------------------------------------
// Gather aggregation from FP16 t', shfl-sourced, wave-convergent (R11 form).
// One wave per node; 16-lane quarter per edge, lane = 4 fp16 features (8B).
// Main loop = G full groups of 16 edges (lockstep shfl, 16 gathers in
// flight); tail = uniform steps, clamped shfl + predicated accumulate.
// out[n] = relu( dinv[n] * ( sum_e t'[src_e] + t'[n] ) )   (fp32 out)
// ---------------------------------------------------------------------------
template <int D>
__global__ __launch_bounds__(256) void agg_kernel(const __half* __restrict__ t,
                                                  const int* __restrict__ rowptr,
                                                  const int* __restrict__ rec,
                                                  const float* __restrict__ dinv,
                                                  float* __restrict__ out, int N) {
    int n = blockIdx.x * 4 + (threadIdx.x >> 6);
    if (n >= N) return;
    const int lane = threadIdx.x & 63;
    const int q  = lane >> 4;          // quarter 0..3
    const int fl = (lane & 15) * 4;    // feature base
    const bool act = (fl < D);
    const int beg = rowptr[n], end = rowptr[n + 1];
    const int deg = end - beg;

    float ax = 0.f, ay = 0.f, az = 0.f, aw = 0.f;
    if (q == 0 && act) {   // self-loop: t'[n]
        uint2 raw = *reinterpret_cast<const uint2*>(&t[(size_t)n * D + fl]);
        float2 f0 = __half22float2(*reinterpret_cast<const __half2*>(&raw.x));
        float2 f1 = __half22float2(*reinterpret_cast<const __half2*>(&raw.y));
        ax = f0.x; ay = f0.y; az = f1.x; aw = f1.y;
    }

    for (int base = 0; base < deg; base += 64) {
        int idx = base + lane;
        int rc = (idx < deg) ? rec[beg + idx] : 0;   // coalesced, 64 edges/load
        const int lim = min(deg - base, 64);         // wave-uniform
        const int G = lim >> 4;                      // full groups of 16 (uniform)
        int j = q;
        for (int g = 0; g < G; ++g, j += 16) {       // lockstep across quarters
            int s0 = __shfl(rc, j);
            int s1 = __shfl(rc, j + 4);
            int s2 = __shfl(rc, j + 8);
            int s3 = __shfl(rc, j + 12);
            if (act) {
                uint2 r0 = *reinterpret_cast<const uint2*>(&t[(size_t)s0 * D + fl]);
                uint2 r1 = *reinterpret_cast<const uint2*>(&t[(size_t)s1 * D + fl]);
                uint2 r2 = *reinterpret_cast<const uint2*>(&t[(size_t)s2 * D + fl]);
                uint2 r3 = *reinterpret_cast<const uint2*>(&t[(size_t)s3 * D + fl]);
                float2 a0 = __half22float2(*reinterpret_cast<const __half2*>(&r0.x));
                float2 b0 = __half22float2(*reinterpret_cast<const __half2*>(&r0.y));
                float2 a1 = __half22float2(*reinterpret_cast<const __half2*>(&r1.x));
                float2 b1 = __half22float2(*reinterpret_cast<const __half2*>(&r1.y));
                float2 a2 = __half22float2(*reinterpret_cast<const __half2*>(&r2.x));
                float2 b2 = __half22float2(*reinterpret_cast<const __half2*>(&r2.y));
                float2 a3 = __half22float2(*reinterpret_cast<const __half2*>(&r3.x));
                float2 b3 = __half22float2(*reinterpret_cast<const __half2*>(&r3.y));
                ax += a0.x; ay += a0.y; az += b0.x; aw += b0.y;
                ax += a1.x; ay += a1.y; az += b1.x; aw += b1.y;
                ax += a2.x; ay += a2.y; az += b2.x; aw += b2.y;
                ax += a3.x; ay += a3.y; az += b3.x; aw += b3.y;
            }
        }
        // tail: r in [0,16); uniform step count, shfl outside divergence
        const int r = lim - (G << 4);
        const int steps = (r + 3) >> 2;              // wave-uniform 0..4
        for (int s = 0; s < steps; ++s, j += 4) {
            int jj = (j < lim) ? j : 0;              // clamp for convergent shfl
            int sn = __shfl(rc, jj);
            if (act && j < lim) {
                uint2 rr = *reinterpret_cast<const uint2*>(&t[(size_t)sn * D + fl]);
                float2 f0 = __half22float2(*reinterpret_cast<const __half2*>(&rr.x));
                float2 f1 = __half22float2(*reinterpret_cast<const __half2*>(&rr.y));
                ax += f0.x; ay += f0.y; az += f1.x; aw += f1.y;
            }
        }
    }

    ax += __shfl_xor(ax, 16); ay += __shfl_xor(ay, 16);
    az += __shfl_xor(az, 16); aw += __shfl_xor(aw, 16);
    ax += __shfl_xor(ax, 32); ay += __shfl_xor(ay, 32);
    az += __shfl_xor(az, 32); aw += __shfl_xor(aw, 32);

    if (q == 0 && act) {
        float di = dinv[n];
        float4 o = make_float4(fmaxf(di * ax, 0.f), fmaxf(di * ay, 0.f),
                               fmaxf(di * az, 0.f), fmaxf(di * aw, 0.f));
        *reinterpret_cast<float4*>(&out[(size_t)n * D + fl]) = o;
    }
}

extern "C" void kernel_launch(void* const* d_in, const int* in_sizes, int n_in,
                              void* d_out, int out_size, void* d_ws, size_t ws_size,
                              hipStream_t stream) {
    const float* x  = (const float*)d_in[0];
    const int*   ei = (const int*)d_in[1];   // [2, E] row-major, int32
    const float* W0 = (const float*)d_in[2]; // [128,64]
    const float* W1 = (const float*)d_in[3]; // [64,64]
    const float* W2 = (const float*)d_in[4]; // [64,40]
    float* out = (float*)d_out;

    const int N = in_sizes[0] / 128;
    const int E = in_sizes[1] / 2;
    const int* src = ei;
    const int* dst = ei + E;
    const int NP = (N + 255) / 256;          // 391 partitions of 256 nodes
    const int histItems = NP * NBLK;         // 200192

    char* w = (char*)d_ws;
    size_t off = 0;
    auto alloc = [&](size_t bytes) {
        void* p = w + off;
        off += bytes;
        off = (off + 255) & ~(size_t)255;
        return p;
    };
    float*    dinv   = (float*)alloc((size_t)N * 4);
    int*      histS  = (int*)alloc((size_t)histItems * 4);   // per-chunk scan (raw)
    int*      rowptr = (int*)alloc((size_t)(N + 1) * 4);
    int*      bsums  = (int*)alloc(4096);
    int*      rec    = (int*)alloc((size_t)E * 4);     // per-node CSR (persists)
    float*    B2     = (float*)alloc((size_t)N * 64 * 4);   // fp32 agg-out / gemm-in
    __half*   tP     = (__half*)alloc((size_t)N * 64 * 2);  // fp16 t' (gathered)
    int*      histG  = (int*)alloc((size_t)histItems * 4);  // raw histogram
    unsigned* recP   = (unsigned*)tP;   // partition-sorted recs, dead before gemm0

    // --- CSR build (counting sort, zero global atomics; reused by 3 layers) ---
    passA_kernel<<<NBLK, 256, 0, stream>>>(dst, E, histG, NP);
    const int nCh = (histItems + SCAN_CHUNK - 1) / SCAN_CHUNK;   // 49
    scan1_kernel<<<nCh, 256, 0, stream>>>(histG, histS, bsums, histItems);
    scan2_kernel<<<1, 64, 0, stream>>>(bsums, nCh);
    passB_kernel<<<NBLK, 256, 0, stream>>>(src, dst, histS, bsums, recP, E, NP);
    passC_kernel<<<NP, 256, 0, stream>>>(recP, histS, bsums, rec, rowptr, dinv, N, E, NP);

    const int gemmGrid = (N + 63) / 64;

    // --- layer 0 ---
    gemm_kernel<128, 64><<<gemmGrid, 256, 0, stream>>>(x, W0, dinv, tP, N);
    agg_kernel<64><<<(N + 3) / 4, 256, 0, stream>>>(tP, rowptr, rec, dinv, B2, N);

    // --- layer 1 ---
    gemm_kernel<64, 64><<<gemmGrid, 256, 0, stream>>>(B2, W1, dinv, tP, N);
    agg_kernel<64><<<(N + 3) / 4, 256, 0, stream>>>(tP, rowptr, rec, dinv, B2, N);

    // --- layer 2 ---
    gemm_kernel<64, 40><<<gemmGrid, 256, 0, stream>>>(B2, W2, dinv, tP, N);
    agg_kernel<40><<<(N + 3) / 4, 256, 0, stream>>>(tP, rowptr, rec, dinv, out, N);
}